// Round 8
// baseline (1966.576 us; speedup 1.0000x reference)
//
#include <hip/hip_runtime.h>
#include <hip/hip_bf16.h>
#include <stdint.h>

// Problem constants (QKVParallelLinearWithLoRA)
#define S_TOK 16384
#define DIN   4096
#define OUTQ  4096
#define OUTKV 1024
#define NOUT  6144   // OUTQ + 2*OUTKV
#define LRANK 64

typedef __attribute__((ext_vector_type(8))) short bf16x8;           // 8 bf16 = 4 VGPR
typedef __attribute__((ext_vector_type(4))) float f32x4;            // MFMA acc frag
typedef __attribute__((ext_vector_type(4))) unsigned short u16x4;   // 4 bf16 store

static __device__ __forceinline__ unsigned short f2bf(float f) {
  uint32_t u = __float_as_uint(f);
  u += 0x7FFFu + ((u >> 16) & 1u);
  return (unsigned short)(u >> 16);
}

static __device__ __forceinline__ void gload_lds16(const void* g, void* l) {
  __builtin_amdgcn_global_load_lds((const __attribute__((address_space(1))) void*)g,
                                   (__attribute__((address_space(3))) void*)l,
                                   16, 0, 0);
}

// ---------------------------------------------------------------------------
// Kernel 1: x fp32 -> bf16
// ---------------------------------------------------------------------------
__global__ __launch_bounds__(256) void cvt_f32_bf16(const float* __restrict__ in,
                                                    unsigned short* __restrict__ out,
                                                    int n4) {
  int i = blockIdx.x * blockDim.x + threadIdx.x;
  const int stride = gridDim.x * blockDim.x;
  const float4* in4 = (const float4*)in;
  for (; i < n4; i += stride) {
    float4 v = in4[i];
    u16x4 o;
    o.x = f2bf(v.x); o.y = f2bf(v.y); o.z = f2bf(v.z); o.w = f2bf(v.w);
    *(u16x4*)(out + (size_t)i * 4) = o;
  }
}

// ---------------------------------------------------------------------------
// Kernel 2: W_eff[o][d] = W[o][d] + sum_r B_seg[o'][r] * A[seg*64+r][d] -> bf16
// ---------------------------------------------------------------------------
__global__ __launch_bounds__(256) void prep_weff(const float* __restrict__ W,
                                                 const float* __restrict__ A,
                                                 const float* __restrict__ Bq,
                                                 const float* __restrict__ Bk,
                                                 const float* __restrict__ Bv,
                                                 unsigned short* __restrict__ Weff) {
  __shared__ float As_[64][128];
  __shared__ float Bs_[64][64];
  const int o0 = blockIdx.x * 64;
  const int d0 = blockIdx.y * 128;
  const int t = threadIdx.x;

  const float* Bseg; int seg, ob;
  if (o0 < OUTQ)              { seg = 0; Bseg = Bq; ob = o0; }
  else if (o0 < OUTQ + OUTKV) { seg = 1; Bseg = Bk; ob = o0 - OUTQ; }
  else                        { seg = 2; Bseg = Bv; ob = o0 - OUTQ - OUTKV; }

  {
    const float4* src = (const float4*)(Bseg + (size_t)ob * LRANK);
    float4* dst = (float4*)&Bs_[0][0];
    for (int i = t; i < 64 * 64 / 4; i += 256) dst[i] = src[i];
  }
  for (int i = t; i < 64 * 32; i += 256) {
    int r = i >> 5, c4 = i & 31;
    *(float4*)&As_[r][c4 * 4] =
        *(const float4*)(A + (size_t)(seg * 64 + r) * DIN + d0 + c4 * 4);
  }
  __syncthreads();

  const int tx = t & 31;
  const int tg = t >> 5;
  for (int oi = tg * 8; oi < tg * 8 + 8; ++oi) {
    const int o = o0 + oi;
    float4 acc = *(const float4*)(W + (size_t)o * DIN + d0 + tx * 4);
#pragma unroll 8
    for (int r = 0; r < 64; ++r) {
      const float b = Bs_[oi][r];
      const float4 a = *(const float4*)&As_[r][tx * 4];
      acc.x += b * a.x; acc.y += b * a.y; acc.z += b * a.z; acc.w += b * a.w;
    }
    u16x4 ov;
    ov.x = f2bf(acc.x); ov.y = f2bf(acc.y); ov.z = f2bf(acc.z); ov.w = f2bf(acc.w);
    *(u16x4*)(Weff + (size_t)o * DIN + d0 + tx * 4) = ov;
  }
}

// ---------------------------------------------------------------------------
// Kernel 3: 256x256 GEMM, BK=64, A DIRECT-FROM-GLOBAL, B via LDS.
//   C[m,n] = sum_k Xb[m,k]*Wb[n,k] + bias[n]
// Rationale (R4-R7 cycle model): per 2-K-tile group the MFMA pipe (~4966 cyc
// /CU) and LDS pipe (~4100-4600 cyc: 384KB frag reads + 128KB stage writes)
// serialize; schedule tweaks (R5 reg-prefetch, R6 2-block/CU, R7 32x32) were
// all null/negative. This kernel removes the A-fragment reads (256KB/group,
// 2/3 of read traffic) from LDS: each wave global-loads its 16 A-frags/tile
// directly to VGPRs (16-row x 64B coalesced; K64 working set/CU = 32KB =
// L1-size, 4x intra-CU reuse; rectangle swizzle keeps per-XCD L2 demand at
// 8 slices). B keeps the R4 staging+read pattern (measured 0 conflicts).
// LDS/K64 = 32KB write + 64KB read ~ 860 cyc << MFMA 2483 cyc -> MFMA-bound.
// Register waits for A-frags/B-frags are left to the compiler (it emits
// correct fine-grained vmcnt/lgkmcnt for reg uses); the ONLY manual sync is
// the gload_lds visibility: vmcnt(0)+barrier once per tile, where the B
// stage loads are a full tile old (no stall) and next tile's A-loads are
// not yet issued (nothing useful drained).
// 8 waves (2M x 4N), wave tile 128x64, 64 x mfma_16x16x32_bf16 per tile.
// ---------------------------------------------------------------------------
__global__ __launch_bounds__(512, 1) void gemm_bt_bias(const unsigned short* __restrict__ Xb,
                                                       const unsigned short* __restrict__ Wb,
                                                       const float* __restrict__ bias,
                                                       float* __restrict__ C) {
  __shared__ unsigned short Blds[32768];  // [buf][ks][256 rows][32 k] = 4x16KB

  // 2-D co-residency swizzle (R4: FETCH 3.2x lower): XCD x owns mt-band
  // [8x,8x+8); 32 concurrent slots tile 8mt x 4nt; generations sweep nt.
  const int bid = blockIdx.x;
  const int x = bid & 7;
  const int l = bid >> 3;
  const int g = l >> 5;
  const int i5 = l & 31;
  const int mt = x * 8 + (i5 & 7);
  const int nt = g * 4 + (i5 >> 3);
  const int m0 = mt * 256;
  const int n0 = nt * 256;

  const int t = threadIdx.x;
  const int lane = t & 63;
  const int w = t >> 6;
  const int wm = (w >> 2) * 128;          // 2 waves in M
  const int wn = (w & 3) * 64;            // 4 waves in N

  // ---- B staging (R4-identical): thread t -> region row t>>2 (+128 for 2nd
  // gload), phys 16B-slot t&3; logical k-slot = (t&3)^((trow>>1)&3) (inverse
  // swizzle on the GLOBAL source; linear gload_lds dest -- rule #21).
  const int trow = t >> 2;
  const int ksl = (t & 3) ^ ((trow >> 1) & 3);
  const size_t gB0 = (size_t)(n0 + trow) * DIN + ksl * 8;
  const size_t gB1 = (size_t)(n0 + 128 + trow) * DIN + ksl * 8;
  const int ldst = t * 8;

#define STAGE_B(T, kh) do {                                                   \
    const int rb_ = (((T) & 1) * 2 + (kh)) * 8192;                            \
    const size_t ko_ = (size_t)((T) * 64 + (kh) * 32);                        \
    gload_lds16(Wb + gB0 + ko_, &Blds[rb_ + ldst]);                           \
    gload_lds16(Wb + gB1 + ko_, &Blds[rb_ + 4096 + ldst]);                    \
  } while (0)

  // ---- B fragment read offsets (R4-identical, measured 0 conflicts)
  const int lr = lane & 15;
  const int ks16 = (lane >> 4) * 16;
  const int fxor = ((lr >> 1) & 3) << 4;
  const int boff = ((wn + lr) * 64 + ks16) ^ fxor;

  // ---- A direct-load base pointers: 8 row-addresses (one per mi), each
  // covers (ks, T) via +64B imm and +128B/tile induction. Per-instr pattern:
  // lanes cover 16 rows x 4 x 16B slices = 16 full 64B lines.
  const unsigned short* aptr[8];
#pragma unroll
  for (int mi = 0; mi < 8; ++mi)
    aptr[mi] = Xb + (size_t)(m0 + wm + mi * 16 + lr) * DIN + (lane >> 4) * 8;

  f32x4 acc[8][4];
#pragma unroll
  for (int i = 0; i < 8; ++i)
#pragma unroll
    for (int j = 0; j < 4; ++j)
      acc[i][j] = f32x4{0.f, 0.f, 0.f, 0.f};

  // prologue: stage B tile 0, drain, barrier.
  STAGE_B(0, 0); STAGE_B(0, 1);
  asm volatile("s_waitcnt vmcnt(0)" ::: "memory");
  __builtin_amdgcn_s_barrier();

  for (int T = 0; T < 64; ++T) {
    const int buf = T & 1;
    if (T < 63) { STAGE_B(T + 1, 0); STAGE_B(T + 1, 1); }  // 4 gload_lds

    const char* Br0 = (const char*)Blds + (buf * 2 + 0) * 16384;
    const char* Br1 = (const char*)Blds + (buf * 2 + 1) * 16384;

#pragma unroll
    for (int ks = 0; ks < 2; ++ks) {
      // A frags for this k-slice: 8 direct global loads (compiler schedules
      // issue early / waits late; free to hoist across the ks loop).
      bf16x8 af[8];
#pragma unroll
      for (int mi = 0; mi < 8; ++mi)
        af[mi] = *(const bf16x8*)(aptr[mi] + T * 64 + ks * 32);
      // B frags from LDS
      const char* Br = ks ? Br1 : Br0;
      bf16x8 bq[4];
#pragma unroll
      for (int ni = 0; ni < 4; ++ni)
        bq[ni] = *(const bf16x8*)(Br + boff + ni * 1024);

      __builtin_amdgcn_s_setprio(1);
#pragma unroll
      for (int mi = 0; mi < 8; ++mi)
#pragma unroll
        for (int ni = 0; ni < 4; ++ni)
          acc[mi][ni] = __builtin_amdgcn_mfma_f32_16x16x32_bf16(af[mi], bq[ni],
                                                                acc[mi][ni], 0, 0, 0);
      __builtin_amdgcn_s_setprio(0);
    }

    // visibility for next tile's B (stage loads are one full tile old ->
    // near-zero stall) + WAR fence for buf swap. Next tile's A-loads are
    // after this point, so nothing useful is drained.
    asm volatile("s_waitcnt vmcnt(0)" ::: "memory");
    __builtin_amdgcn_s_barrier();
  }
#undef STAGE_B

  // epilogue: C/D layout col=lane&15, row=(lane>>4)*4+reg (m89/m91-verified)
  const int cr4 = (lane >> 4) * 4;
#pragma unroll
  for (int ni = 0; ni < 4; ++ni) {
    const int col = n0 + wn + ni * 16 + lr;
    const float bv = bias[col];
#pragma unroll
    for (int mi = 0; mi < 8; ++mi) {
      const int row = m0 + wm + mi * 16 + cr4;
#pragma unroll
      for (int jj = 0; jj < 4; ++jj)
        C[(size_t)(row + jj) * NOUT + col] = acc[mi][ni][jj] + bv;
    }
  }
}

// ---------------------------------------------------------------------------
extern "C" void kernel_launch(void* const* d_in, const int* in_sizes, int n_in,
                              void* d_out, int out_size, void* d_ws, size_t ws_size,
                              hipStream_t stream) {
  const float* x    = (const float*)d_in[0];
  const float* Wqkv = (const float*)d_in[1];
  const float* bias = (const float*)d_in[2];
  const float* Aq   = (const float*)d_in[3];
  const float* Bq   = (const float*)d_in[4];
  const float* Bk   = (const float*)d_in[5];
  const float* Bv   = (const float*)d_in[6];
  float* out = (float*)d_out;

  unsigned short* xb = (unsigned short*)d_ws;                 // 128 MB
  unsigned short* wb = xb + (size_t)S_TOK * DIN;              // 48 MB

  cvt_f32_bf16<<<2048, 256, 0, stream>>>(x, xb, S_TOK * DIN / 4);

  dim3 g1(NOUT / 64, DIN / 128);
  prep_weff<<<g1, 256, 0, stream>>>(Wqkv, Aq, Bq, Bk, Bv, wb);

  gemm_bt_bias<<<1536, 512, 0, stream>>>(xb, wb, bias, out);
}

// Round 9
// 916.053 us; speedup vs baseline: 2.1468x; 2.1468x over previous
//
#include <hip/hip_runtime.h>
#include <hip/hip_bf16.h>
#include <stdint.h>

// Problem constants (QKVParallelLinearWithLoRA)
#define S_TOK 16384
#define DIN   4096
#define OUTQ  4096
#define OUTKV 1024
#define NOUT  6144   // OUTQ + 2*OUTKV
#define LRANK 64

typedef __attribute__((ext_vector_type(8))) short bf16x8;           // 8 bf16 = 4 VGPR
typedef __attribute__((ext_vector_type(4))) float f32x4;            // MFMA acc frag
typedef __attribute__((ext_vector_type(4))) unsigned short u16x4;   // 4 bf16 store

static __device__ __forceinline__ unsigned short f2bf(float f) {
  uint32_t u = __float_as_uint(f);
  u += 0x7FFFu + ((u >> 16) & 1u);
  return (unsigned short)(u >> 16);
}

static __device__ __forceinline__ void gload_lds16(const void* g, void* l) {
  __builtin_amdgcn_global_load_lds((const __attribute__((address_space(1))) void*)g,
                                   (__attribute__((address_space(3))) void*)l,
                                   16, 0, 0);
}

// ---------------------------------------------------------------------------
// Kernel 1: x fp32 -> bf16
// ---------------------------------------------------------------------------
__global__ __launch_bounds__(256) void cvt_f32_bf16(const float* __restrict__ in,
                                                    unsigned short* __restrict__ out,
                                                    int n4) {
  int i = blockIdx.x * blockDim.x + threadIdx.x;
  const int stride = gridDim.x * blockDim.x;
  const float4* in4 = (const float4*)in;
  for (; i < n4; i += stride) {
    float4 v = in4[i];
    u16x4 o;
    o.x = f2bf(v.x); o.y = f2bf(v.y); o.z = f2bf(v.z); o.w = f2bf(v.w);
    *(u16x4*)(out + (size_t)i * 4) = o;
  }
}

// ---------------------------------------------------------------------------
// Kernel 2: W_eff[o][d] = W[o][d] + sum_r B_seg[o'][r] * A[seg*64+r][d] -> bf16
// ---------------------------------------------------------------------------
__global__ __launch_bounds__(256) void prep_weff(const float* __restrict__ W,
                                                 const float* __restrict__ A,
                                                 const float* __restrict__ Bq,
                                                 const float* __restrict__ Bk,
                                                 const float* __restrict__ Bv,
                                                 unsigned short* __restrict__ Weff) {
  __shared__ float As_[64][128];
  __shared__ float Bs_[64][64];
  const int o0 = blockIdx.x * 64;
  const int d0 = blockIdx.y * 128;
  const int t = threadIdx.x;

  const float* Bseg; int seg, ob;
  if (o0 < OUTQ)              { seg = 0; Bseg = Bq; ob = o0; }
  else if (o0 < OUTQ + OUTKV) { seg = 1; Bseg = Bk; ob = o0 - OUTQ; }
  else                        { seg = 2; Bseg = Bv; ob = o0 - OUTQ - OUTKV; }

  {
    const float4* src = (const float4*)(Bseg + (size_t)ob * LRANK);
    float4* dst = (float4*)&Bs_[0][0];
    for (int i = t; i < 64 * 64 / 4; i += 256) dst[i] = src[i];
  }
  for (int i = t; i < 64 * 32; i += 256) {
    int r = i >> 5, c4 = i & 31;
    *(float4*)&As_[r][c4 * 4] =
        *(const float4*)(A + (size_t)(seg * 64 + r) * DIN + d0 + c4 * 4);
  }
  __syncthreads();

  const int tx = t & 31;
  const int tg = t >> 5;
  for (int oi = tg * 8; oi < tg * 8 + 8; ++oi) {
    const int o = o0 + oi;
    float4 acc = *(const float4*)(W + (size_t)o * DIN + d0 + tx * 4);
#pragma unroll 8
    for (int r = 0; r < 64; ++r) {
      const float b = Bs_[oi][r];
      const float4 a = *(const float4*)&As_[r][tx * 4];
      acc.x += b * a.x; acc.y += b * a.y; acc.z += b * a.z; acc.w += b * a.w;
    }
    u16x4 ov;
    ov.x = f2bf(acc.x); ov.y = f2bf(acc.y); ov.z = f2bf(acc.z); ov.w = f2bf(acc.w);
    *(u16x4*)(Weff + (size_t)o * DIN + d0 + tx * 4) = ov;
  }
}

// ---------------------------------------------------------------------------
// Kernel 3: 256x256 GEMM, BK=64, 8-phase, LOOSE phases (one variable vs R4):
// the mid-phase {s_barrier; lgkmcnt(0); sched_barrier} pin is REMOVED. R4's
// measured phase (1266 cyc) = DS window (576, round-robin -> all waves'
// reads complete together) + MFMA window (621), serialized by that pin.
// Without it the compiler emits fine-grained lgkmcnt before each consuming
// MFMA (m97 asm evidence), so a wave's early MFMAs overlap the DS window.
// Race safety: every ds_read's consumer MFMA precedes the phase-end barrier
// (compiler waits guarantee read completion before barrier); staging RAW/WAR
// ledger is byte-identical to R4: stage rotation, counted vmcnt(4) at even
// phases (never 0 in main loop), stage->read distance >= 2 phases.
//   C[m,n] = sum_k Xb[m,k]*Wb[n,k] + bias[n]
// 8 waves (2M x 4N), wave tile 128x64 = 8x4 frags of 16x16x32 bf16 MFMA.
// LDS: A/B x [2 buf][2 kh][256 rows][32 k] = 128 KiB. Swizzle (T2):
// byte ^= ((row>>1)&3)<<4 on tile-local offsets, inverse-applied to the
// GLOBAL source (linear gload_lds dest, rule #21) -- R4 measured 0 conflicts.
// 2-D co-residency XCD swizzle (R4: FETCH 3.2x lower).
// ---------------------------------------------------------------------------
__global__ __launch_bounds__(512, 1) void gemm_bt_bias(const unsigned short* __restrict__ Xb,
                                                       const unsigned short* __restrict__ Wb,
                                                       const float* __restrict__ bias,
                                                       float* __restrict__ C) {
  __shared__ unsigned short Alds[32768];  // [buf][kh][256 rows][32 k] = 4x16KB
  __shared__ unsigned short Blds[32768];

  const int bid = blockIdx.x;
  const int x = bid & 7;
  const int l = bid >> 3;
  const int g = l >> 5;
  const int i5 = l & 31;
  const int mt = x * 8 + (i5 & 7);
  const int nt = g * 4 + (i5 >> 3);
  const int m0 = mt * 256;
  const int n0 = nt * 256;

  const int t = threadIdx.x;
  const int lane = t & 63;
  const int w = t >> 6;
  const int wm = (w >> 2) * 128;          // 2 waves in M
  const int wn = (w & 3) * 64;            // 4 waves in N

  // staging: thread t -> region row t>>2 (+128 for 2nd gload), phys 16B-slot
  // t&3; logical k-slot = (t&3)^((trow>>1)&3) (inverse swizzle on source).
  const int trow = t >> 2;
  const int ksl = (t & 3) ^ ((trow >> 1) & 3);
  const size_t gA0 = (size_t)(m0 + trow) * DIN + ksl * 8;
  const size_t gA1 = (size_t)(m0 + 128 + trow) * DIN + ksl * 8;
  const size_t gB0 = (size_t)(n0 + trow) * DIN + ksl * 8;
  const size_t gB1 = (size_t)(n0 + 128 + trow) * DIN + ksl * 8;
  const int ldst = t * 8;

#define STAGE_A(T, kh) do {                                                   \
    const int rb_ = (((T) & 1) * 2 + (kh)) * 8192;                            \
    const size_t ko_ = (size_t)((T) * 64 + (kh) * 32);                        \
    gload_lds16(Xb + gA0 + ko_, &Alds[rb_ + ldst]);                           \
    gload_lds16(Xb + gA1 + ko_, &Alds[rb_ + 4096 + ldst]);                    \
  } while (0)
#define STAGE_B(T, kh) do {                                                   \
    const int rb_ = (((T) & 1) * 2 + (kh)) * 8192;                            \
    const size_t ko_ = (size_t)((T) * 64 + (kh) * 32);                        \
    gload_lds16(Wb + gB0 + ko_, &Blds[rb_ + ldst]);                           \
    gload_lds16(Wb + gB1 + ko_, &Blds[rb_ + 4096 + ldst]);                    \
  } while (0)

  // fragment read offsets (bytes within 16KB region)
  const int lr = lane & 15;
  const int ks16 = (lane >> 4) * 16;
  const int fxor = ((lr >> 1) & 3) << 4;
  const int aoff = ((wm + lr) * 64 + ks16) ^ fxor;
  const int boff = ((wn + lr) * 64 + ks16) ^ fxor;

  f32x4 acc[8][4];
#pragma unroll
  for (int i = 0; i < 8; ++i)
#pragma unroll
    for (int j = 0; j < 4; ++j)
      acc[i][j] = f32x4{0.f, 0.f, 0.f, 0.f};
  bf16x8 bq[4];

#define END_P()  __builtin_amdgcn_s_barrier()
#define END_V4() do { asm volatile("s_waitcnt vmcnt(4)" ::: "memory");        \
                      __builtin_amdgcn_s_barrier(); } while (0)
#define END_V0() do { asm volatile("s_waitcnt vmcnt(0)" ::: "memory");        \
                      __builtin_amdgcn_s_barrier(); } while (0)

  // PH: reads -> stage-issue -> MFMA (compiler-scheduled fine lgkm waits;
  // NO mid barrier, NO lgkmcnt(0) pin) -> phase-end barrier (ENDM).
#define PH(buf, ks, fh, STAGE_STMT, ENDM) do {                                \
    const char* Ar_ = (const char*)&Alds[((buf) * 2 + (ks)) * 8192];          \
    const char* Br_ = (const char*)&Blds[((buf) * 2 + (ks)) * 8192];          \
    bf16x8 af_[4];                                                            \
    if ((fh) == 0) {                                                          \
      _Pragma("unroll")                                                       \
      for (int n_ = 0; n_ < 4; ++n_)                                          \
        bq[n_] = *(const bf16x8*)(Br_ + boff + n_ * 1024);                    \
    }                                                                         \
    _Pragma("unroll")                                                         \
    for (int j_ = 0; j_ < 4; ++j_)                                            \
      af_[j_] = *(const bf16x8*)(Ar_ + aoff + ((fh) * 4 + j_) * 1024);        \
    STAGE_STMT;                                                               \
    __builtin_amdgcn_s_setprio(1);                                            \
    _Pragma("unroll")                                                         \
    for (int j_ = 0; j_ < 4; ++j_)                                            \
      _Pragma("unroll")                                                       \
      for (int n_ = 0; n_ < 4; ++n_)                                          \
        acc[(fh) * 4 + j_][n_] = __builtin_amdgcn_mfma_f32_16x16x32_bf16(     \
            af_[j_], bq[n_], acc[(fh) * 4 + j_][n_], 0, 0, 0);                \
    __builtin_amdgcn_s_setprio(0);                                            \
    ENDM();                                                                   \
  } while (0)

  // prologue: stage tile 0 fully (8 loads, order A0,B0,A1,B1); wait oldest 4.
  STAGE_A(0, 0); STAGE_B(0, 0); STAGE_A(0, 1); STAGE_B(0, 1);
  END_V4();

  // main loop: 31 iterations, tiles 0..61; tile 62 staged by i=30 phases 5-8.
  // (identical rotation + vmcnt ledger to R4, which ran race-free)
  for (int i = 0; i < 31; ++i) {
    const int T1 = 2 * i + 1, T2 = 2 * i + 2;
    PH(0, 0, 0, STAGE_A(T1, 0), END_P);   // p1
    PH(0, 0, 1, STAGE_B(T1, 0), END_V4);  // p2: tile2i A1,B1 land
    PH(0, 1, 0, STAGE_A(T1, 1), END_P);   // p3
    PH(0, 1, 1, STAGE_B(T1, 1), END_V4);  // p4: tile2i+1 A0,B0 land
    PH(1, 0, 0, STAGE_A(T2, 0), END_P);   // p5
    PH(1, 0, 1, STAGE_B(T2, 0), END_V4);  // p6: tile2i+1 A1,B1 land
    PH(1, 1, 0, STAGE_A(T2, 1), END_P);   // p7
    PH(1, 1, 1, STAGE_B(T2, 1), END_V4);  // p8: tile2i+2 A0,B0 land
  }
  // final iteration (tiles 62, 63): stage only tile 63; drain 4 -> 4 -> 0.
  PH(0, 0, 0, STAGE_A(63, 0), END_P);
  PH(0, 0, 1, STAGE_B(63, 0), END_V4);    // tile62 A1,B1 land
  PH(0, 1, 0, STAGE_A(63, 1), END_P);
  PH(0, 1, 1, STAGE_B(63, 1), END_V4);    // tile63 A0,B0 land
  PH(1, 0, 0, ((void)0), END_P);
  PH(1, 0, 1, ((void)0), END_V0);         // tile63 A1,B1 land
  PH(1, 1, 0, ((void)0), END_P);
  PH(1, 1, 1, ((void)0), END_P);

#undef PH
#undef STAGE_A
#undef STAGE_B
#undef END_P
#undef END_V4
#undef END_V0

  // epilogue: C/D layout col=lane&15, row=(lane>>4)*4+reg (m89/m91-verified)
  const int cr4 = (lane >> 4) * 4;
#pragma unroll
  for (int ni = 0; ni < 4; ++ni) {
    const int col = n0 + wn + ni * 16 + lr;
    const float bv = bias[col];
#pragma unroll
    for (int mi = 0; mi < 8; ++mi) {
      const int row = m0 + wm + mi * 16 + cr4;
#pragma unroll
      for (int jj = 0; jj < 4; ++jj)
        C[(size_t)(row + jj) * NOUT + col] = acc[mi][ni][jj] + bv;
    }
  }
}

// ---------------------------------------------------------------------------
extern "C" void kernel_launch(void* const* d_in, const int* in_sizes, int n_in,
                              void* d_out, int out_size, void* d_ws, size_t ws_size,
                              hipStream_t stream) {
  const float* x    = (const float*)d_in[0];
  const float* Wqkv = (const float*)d_in[1];
  const float* bias = (const float*)d_in[2];
  const float* Aq   = (const float*)d_in[3];
  const float* Bq   = (const float*)d_in[4];
  const float* Bk   = (const float*)d_in[5];
  const float* Bv   = (const float*)d_in[6];
  float* out = (float*)d_out;

  unsigned short* xb = (unsigned short*)d_ws;                 // 128 MB
  unsigned short* wb = xb + (size_t)S_TOK * DIN;              // 48 MB

  cvt_f32_bf16<<<2048, 256, 0, stream>>>(x, xb, S_TOK * DIN / 4);

  dim3 g1(NOUT / 64, DIN / 128);
  prep_weff<<<g1, 256, 0, stream>>>(Wqkv, Aq, Bq, Bk, Bv, wb);

  gemm_bt_bias<<<1536, 512, 0, stream>>>(xb, wb, bias, out);
}

// Round 10
// 894.001 us; speedup vs baseline: 2.1997x; 1.0247x over previous
//
#include <hip/hip_runtime.h>
#include <hip/hip_bf16.h>
#include <stdint.h>

// Problem constants (QKVParallelLinearWithLoRA)
#define S_TOK 16384
#define DIN   4096
#define OUTQ  4096
#define OUTKV 1024
#define NOUT  6144   // OUTQ + 2*OUTKV
#define LRANK 64

typedef __attribute__((ext_vector_type(8))) short bf16x8;           // 8 bf16 = 4 VGPR
typedef __attribute__((ext_vector_type(4))) float f32x4;            // MFMA acc frag
typedef __attribute__((ext_vector_type(4))) unsigned short u16x4;   // 4 bf16 store

static __device__ __forceinline__ unsigned short f2bf(float f) {
  uint32_t u = __float_as_uint(f);
  u += 0x7FFFu + ((u >> 16) & 1u);
  return (unsigned short)(u >> 16);
}

static __device__ __forceinline__ void gload_lds16(const void* g, void* l) {
  __builtin_amdgcn_global_load_lds((const __attribute__((address_space(1))) void*)g,
                                   (__attribute__((address_space(3))) void*)l,
                                   16, 0, 0);
}

// ---------------------------------------------------------------------------
// Kernel 1: x fp32 -> bf16
// ---------------------------------------------------------------------------
__global__ __launch_bounds__(256) void cvt_f32_bf16(const float* __restrict__ in,
                                                    unsigned short* __restrict__ out,
                                                    int n4) {
  int i = blockIdx.x * blockDim.x + threadIdx.x;
  const int stride = gridDim.x * blockDim.x;
  const float4* in4 = (const float4*)in;
  for (; i < n4; i += stride) {
    float4 v = in4[i];
    u16x4 o;
    o.x = f2bf(v.x); o.y = f2bf(v.y); o.z = f2bf(v.z); o.w = f2bf(v.w);
    *(u16x4*)(out + (size_t)i * 4) = o;
  }
}

// ---------------------------------------------------------------------------
// Kernel 2: W_eff[o][d] = W[o][d] + sum_r B_seg[o'][r] * A[seg*64+r][d] -> bf16
// ---------------------------------------------------------------------------
__global__ __launch_bounds__(256) void prep_weff(const float* __restrict__ W,
                                                 const float* __restrict__ A,
                                                 const float* __restrict__ Bq,
                                                 const float* __restrict__ Bk,
                                                 const float* __restrict__ Bv,
                                                 unsigned short* __restrict__ Weff) {
  __shared__ float As_[64][128];
  __shared__ float Bs_[64][64];
  const int o0 = blockIdx.x * 64;
  const int d0 = blockIdx.y * 128;
  const int t = threadIdx.x;

  const float* Bseg; int seg, ob;
  if (o0 < OUTQ)              { seg = 0; Bseg = Bq; ob = o0; }
  else if (o0 < OUTQ + OUTKV) { seg = 1; Bseg = Bk; ob = o0 - OUTQ; }
  else                        { seg = 2; Bseg = Bv; ob = o0 - OUTQ - OUTKV; }

  {
    const float4* src = (const float4*)(Bseg + (size_t)ob * LRANK);
    float4* dst = (float4*)&Bs_[0][0];
    for (int i = t; i < 64 * 64 / 4; i += 256) dst[i] = src[i];
  }
  for (int i = t; i < 64 * 32; i += 256) {
    int r = i >> 5, c4 = i & 31;
    *(float4*)&As_[r][c4 * 4] =
        *(const float4*)(A + (size_t)(seg * 64 + r) * DIN + d0 + c4 * 4);
  }
  __syncthreads();

  const int tx = t & 31;
  const int tg = t >> 5;
  for (int oi = tg * 8; oi < tg * 8 + 8; ++oi) {
    const int o = o0 + oi;
    float4 acc = *(const float4*)(W + (size_t)o * DIN + d0 + tx * 4);
#pragma unroll 8
    for (int r = 0; r < 64; ++r) {
      const float b = Bs_[oi][r];
      const float4 a = *(const float4*)&As_[r][tx * 4];
      acc.x += b * a.x; acc.y += b * a.y; acc.z += b * a.z; acc.w += b * a.w;
    }
    u16x4 ov;
    ov.x = f2bf(acc.x); ov.y = f2bf(acc.y); ov.z = f2bf(acc.z); ov.w = f2bf(acc.w);
    *(u16x4*)(Weff + (size_t)o * DIN + d0 + tx * 4) = ov;
  }
}

// ---------------------------------------------------------------------------
// Kernel 3: 256x256 GEMM, BK=64, 8-phase, 2-PHASE WINDOWS (one variable vs
// R9): odd phases lose their s_barrier. Barriers only at even-phase ends
// (with the same counted vmcnt(4)). Within a window the compiler sees 12
// independent ds_read_b128 + 32 MFMA straight-line and interleaves them
// with fine-grained lgkm waits (R9 measured the per-phase barrier kept DS
// and MFMA serialized: 1211 cyc/phase ~ 576 DS + 621 MFMA).
// Ledger re-verified at window granularity (RAW: vmcnt(4) lands each region
// one window before its reads; WAR: every stage separated from prior readers
// by >=1 even barrier; drift bounded by even barriers; tail drains 4->4->0).
//   C[m,n] = sum_k Xb[m,k]*Wb[n,k] + bias[n]
// 8 waves (2M x 4N), wave tile 128x64 = 8x4 frags of 16x16x32 bf16 MFMA.
// LDS: A/B x [2 buf][2 kh][256 rows][32 k] = 128 KiB. Swizzle: byte ^=
// ((row>>1)&3)<<4 inverse-applied to global source (rule #21) -- 0 conflicts.
// 2-D co-residency XCD swizzle (R4: FETCH 3.2x lower).
// ---------------------------------------------------------------------------
__global__ __launch_bounds__(512, 1) void gemm_bt_bias(const unsigned short* __restrict__ Xb,
                                                       const unsigned short* __restrict__ Wb,
                                                       const float* __restrict__ bias,
                                                       float* __restrict__ C) {
  __shared__ unsigned short Alds[32768];  // [buf][kh][256 rows][32 k] = 4x16KB
  __shared__ unsigned short Blds[32768];

  const int bid = blockIdx.x;
  const int x = bid & 7;
  const int l = bid >> 3;
  const int g = l >> 5;
  const int i5 = l & 31;
  const int mt = x * 8 + (i5 & 7);
  const int nt = g * 4 + (i5 >> 3);
  const int m0 = mt * 256;
  const int n0 = nt * 256;

  const int t = threadIdx.x;
  const int lane = t & 63;
  const int w = t >> 6;
  const int wm = (w >> 2) * 128;          // 2 waves in M
  const int wn = (w & 3) * 64;            // 4 waves in N

  // staging: thread t -> region row t>>2 (+128 for 2nd gload), phys 16B-slot
  // t&3; logical k-slot = (t&3)^((trow>>1)&3) (inverse swizzle on source).
  const int trow = t >> 2;
  const int ksl = (t & 3) ^ ((trow >> 1) & 3);
  const size_t gA0 = (size_t)(m0 + trow) * DIN + ksl * 8;
  const size_t gA1 = (size_t)(m0 + 128 + trow) * DIN + ksl * 8;
  const size_t gB0 = (size_t)(n0 + trow) * DIN + ksl * 8;
  const size_t gB1 = (size_t)(n0 + 128 + trow) * DIN + ksl * 8;
  const int ldst = t * 8;

#define STAGE_A(T, kh) do {                                                   \
    const int rb_ = (((T) & 1) * 2 + (kh)) * 8192;                            \
    const size_t ko_ = (size_t)((T) * 64 + (kh) * 32);                        \
    gload_lds16(Xb + gA0 + ko_, &Alds[rb_ + ldst]);                           \
    gload_lds16(Xb + gA1 + ko_, &Alds[rb_ + 4096 + ldst]);                    \
  } while (0)
#define STAGE_B(T, kh) do {                                                   \
    const int rb_ = (((T) & 1) * 2 + (kh)) * 8192;                            \
    const size_t ko_ = (size_t)((T) * 64 + (kh) * 32);                        \
    gload_lds16(Wb + gB0 + ko_, &Blds[rb_ + ldst]);                           \
    gload_lds16(Wb + gB1 + ko_, &Blds[rb_ + 4096 + ldst]);                    \
  } while (0)

  // fragment read offsets (bytes within 16KB region)
  const int lr = lane & 15;
  const int ks16 = (lane >> 4) * 16;
  const int fxor = ((lr >> 1) & 3) << 4;
  const int aoff = ((wm + lr) * 64 + ks16) ^ fxor;
  const int boff = ((wn + lr) * 64 + ks16) ^ fxor;

  f32x4 acc[8][4];
#pragma unroll
  for (int i = 0; i < 8; ++i)
#pragma unroll
    for (int j = 0; j < 4; ++j)
      acc[i][j] = f32x4{0.f, 0.f, 0.f, 0.f};
  bf16x8 bq[4];

#define END_N()  ((void)0)                 // odd phase: no terminator
#define END_V4() do { asm volatile("s_waitcnt vmcnt(4)" ::: "memory");        \
                      __builtin_amdgcn_s_barrier(); } while (0)
#define END_V0() do { asm volatile("s_waitcnt vmcnt(0)" ::: "memory");        \
                      __builtin_amdgcn_s_barrier(); } while (0)

  // PH: reads -> stage-issue -> MFMA (compiler-scheduled lgkm waits) -> ENDM.
#define PH(buf, ks, fh, STAGE_STMT, ENDM) do {                                \
    const char* Ar_ = (const char*)&Alds[((buf) * 2 + (ks)) * 8192];          \
    const char* Br_ = (const char*)&Blds[((buf) * 2 + (ks)) * 8192];          \
    bf16x8 af_[4];                                                            \
    if ((fh) == 0) {                                                          \
      _Pragma("unroll")                                                       \
      for (int n_ = 0; n_ < 4; ++n_)                                          \
        bq[n_] = *(const bf16x8*)(Br_ + boff + n_ * 1024);                    \
    }                                                                         \
    _Pragma("unroll")                                                         \
    for (int j_ = 0; j_ < 4; ++j_)                                            \
      af_[j_] = *(const bf16x8*)(Ar_ + aoff + ((fh) * 4 + j_) * 1024);        \
    STAGE_STMT;                                                               \
    __builtin_amdgcn_s_setprio(1);                                            \
    _Pragma("unroll")                                                         \
    for (int j_ = 0; j_ < 4; ++j_)                                            \
      _Pragma("unroll")                                                       \
      for (int n_ = 0; n_ < 4; ++n_)                                          \
        acc[(fh) * 4 + j_][n_] = __builtin_amdgcn_mfma_f32_16x16x32_bf16(     \
            af_[j_], bq[n_], acc[(fh) * 4 + j_][n_], 0, 0, 0);                \
    __builtin_amdgcn_s_setprio(0);                                            \
    ENDM();                                                                   \
  } while (0)

  // prologue: stage tile 0 fully (8 loads, order A0,B0,A1,B1); wait oldest 4.
  STAGE_A(0, 0); STAGE_B(0, 0); STAGE_A(0, 1); STAGE_B(0, 1);
  END_V4();

  // main loop: 31 iterations, tiles 0..61; tile 62 staged by i=30 phases 5-8.
  // Stage rotation and vmcnt ledger identical to R9 (ran race-free); only
  // the odd-phase barriers are removed (window analysis in header comment).
  for (int i = 0; i < 31; ++i) {
    const int T1 = 2 * i + 1, T2 = 2 * i + 2;
    PH(0, 0, 0, STAGE_A(T1, 0), END_N);   // p1
    PH(0, 0, 1, STAGE_B(T1, 0), END_V4);  // p2: tile2i A1,B1 land
    PH(0, 1, 0, STAGE_A(T1, 1), END_N);   // p3
    PH(0, 1, 1, STAGE_B(T1, 1), END_V4);  // p4: tile2i+1 A0,B0 land
    PH(1, 0, 0, STAGE_A(T2, 0), END_N);   // p5
    PH(1, 0, 1, STAGE_B(T2, 0), END_V4);  // p6: tile2i+1 A1,B1 land
    PH(1, 1, 0, STAGE_A(T2, 1), END_N);   // p7
    PH(1, 1, 1, STAGE_B(T2, 1), END_V4);  // p8: tile2i+2 A0,B0 land
  }
  // final iteration (tiles 62, 63): stage only tile 63; drain 4 -> 4 -> 0.
  PH(0, 0, 0, STAGE_A(63, 0), END_N);
  PH(0, 0, 1, STAGE_B(63, 0), END_V4);    // tile62 A1,B1 land
  PH(0, 1, 0, STAGE_A(63, 1), END_N);
  PH(0, 1, 1, STAGE_B(63, 1), END_V4);    // tile63 A0,B0 land
  PH(1, 0, 0, ((void)0), END_N);
  PH(1, 0, 1, ((void)0), END_V0);         // tile63 A1,B1 land
  PH(1, 1, 0, ((void)0), END_N);
  PH(1, 1, 1, ((void)0), END_N);          // no barrier needed before epilogue

#undef PH
#undef STAGE_A
#undef STAGE_B
#undef END_N
#undef END_V4
#undef END_V0

  // epilogue: C/D layout col=lane&15, row=(lane>>4)*4+reg (m89/m91-verified)
  const int cr4 = (lane >> 4) * 4;
#pragma unroll
  for (int ni = 0; ni < 4; ++ni) {
    const int col = n0 + wn + ni * 16 + lr;
    const float bv = bias[col];
#pragma unroll
    for (int mi = 0; mi < 8; ++mi) {
      const int row = m0 + wm + mi * 16 + cr4;
#pragma unroll
      for (int jj = 0; jj < 4; ++jj)
        C[(size_t)(row + jj) * NOUT + col] = acc[mi][ni][jj] + bv;
    }
  }
}

// ---------------------------------------------------------------------------
extern "C" void kernel_launch(void* const* d_in, const int* in_sizes, int n_in,
                              void* d_out, int out_size, void* d_ws, size_t ws_size,
                              hipStream_t stream) {
  const float* x    = (const float*)d_in[0];
  const float* Wqkv = (const float*)d_in[1];
  const float* bias = (const float*)d_in[2];
  const float* Aq   = (const float*)d_in[3];
  const float* Bq   = (const float*)d_in[4];
  const float* Bk   = (const float*)d_in[5];
  const float* Bv   = (const float*)d_in[6];
  float* out = (float*)d_out;

  unsigned short* xb = (unsigned short*)d_ws;                 // 128 MB
  unsigned short* wb = xb + (size_t)S_TOK * DIN;              // 48 MB

  cvt_f32_bf16<<<2048, 256, 0, stream>>>(x, xb, S_TOK * DIN / 4);

  dim3 g1(NOUT / 64, DIN / 128);
  prep_weff<<<g1, 256, 0, stream>>>(Wqkv, Aq, Bq, Bk, Bv, wb);

  gemm_bt_bias<<<1536, 512, 0, stream>>>(xb, wb, bias, out);
}